// Round 3
// baseline (1229.777 us; speedup 1.0000x reference)
//
#include <hip/hip_runtime.h>
#include <stdint.h>

#define B_ 4096
#define T_ 49
#define H_ 512
#define BT_ (B_*T_)
#define BB 16

typedef __bf16 bf16x8 __attribute__((ext_vector_type(8)));
typedef float  f32x4  __attribute__((ext_vector_type(4)));
typedef unsigned short ushort_;

__device__ __forceinline__ ushort_ f2bf(float f){
  unsigned int u = __float_as_uint(f);
  u += 0x7fffu + ((u >> 16) & 1u);           // RNE
  return (ushort_)(u >> 16);
}

__device__ __forceinline__ float fast_tanh(float x){
  float e = __expf(2.0f * x);
  return 1.0f - 2.0f * __builtin_amdgcn_rcpf(e + 1.0f);
}

// k_pack: Wv [K][N] f32 -> fragment-ordered bf16.
// bpack[((kk*32 + gt)*64 + lane)*8 + e] = bf16(Wv[kk*32 + (lane>>4)*8 + e][gt*16 + (lane&15)])
__global__ __launch_bounds__(256) void k_pack(const float* __restrict__ Wv,
                                              ushort_* __restrict__ bpack){
  int idx = blockIdx.x * 256 + threadIdx.x;   // 0..32767
  int lane = idx & 63;
  int gt   = (idx >> 6) & 31;
  int kk   = idx >> 11;
  int col  = gt*16 + (lane & 15);
  int k0   = kk*32 + (lane >> 4)*8;
  ushort4 lo, hi;
  lo.x = f2bf(Wv[(k0+0)*H_ + col]);
  lo.y = f2bf(Wv[(k0+1)*H_ + col]);
  lo.z = f2bf(Wv[(k0+2)*H_ + col]);
  lo.w = f2bf(Wv[(k0+3)*H_ + col]);
  hi.x = f2bf(Wv[(k0+4)*H_ + col]);
  hi.y = f2bf(Wv[(k0+5)*H_ + col]);
  hi.z = f2bf(Wv[(k0+6)*H_ + col]);
  hi.w = f2bf(Wv[(k0+7)*H_ + col]);
  ushort4* dst = (ushort4*)bpack;
  dst[idx*2]   = lo;
  dst[idx*2+1] = hi;
}

// K1: hpb[b][k] = h@W_h + b_h + b_v ; beta[b] = tanh((s@W_s + b_s + h_proj)*sqrt(.5))@w_beta + b_beta
__global__ __launch_bounds__(512) void k_proj(
    const float* __restrict__ h, const float* __restrict__ s,
    const float* __restrict__ Wh, const float* __restrict__ bh,
    const float* __restrict__ Ws, const float* __restrict__ bs,
    const float* __restrict__ bv, const float* __restrict__ wbeta,
    const float* __restrict__ bbeta_p,
    float* __restrict__ hpb, float* __restrict__ beta)
{
  __shared__ float hs[H_*BB];     // [j][bb] layout
  __shared__ float ssm[H_*BB];
  __shared__ float part[BB][8];
  const int tid = threadIdx.x;
  const int b0 = blockIdx.x * BB;

  for(int idx = tid; idx < H_*BB; idx += 512){
    int bb2 = idx & (BB-1);
    int j   = idx >> 4;
    hs[idx]  = h[(size_t)(b0+bb2)*H_ + j];
    ssm[idx] = s[(size_t)(b0+bb2)*H_ + j];
  }
  __syncthreads();

  const int k = tid;
  float ah[BB], as_[BB];
  #pragma unroll
  for(int i=0;i<BB;i++){ ah[i]=0.f; as_[i]=0.f; }

  #pragma unroll 4
  for(int j=0;j<H_;j++){
    float whv = Wh[j*H_ + k];
    float wsv = Ws[j*H_ + k];
    #pragma unroll
    for(int i=0;i<BB;i++){
      ah[i]  = fmaf(hs[j*BB+i],  whv, ah[i]);
      as_[i] = fmaf(ssm[j*BB+i], wsv, as_[i]);
    }
  }

  const float bhk = bh[k], bsk = bs[k], bvk = bv[k], wbk = wbeta[k];
  const float bbv = bbeta_p[0];
  const int lane = tid & 63, wid = tid >> 6;

  #pragma unroll
  for(int i=0;i<BB;i++){
    float hp = ah[i] + bhk;
    hpb[(size_t)(b0+i)*H_ + k] = hp + bvk;
    float bt = fast_tanh((as_[i] + bsk + hp) * 0.70710678118654752f);
    float c = bt * wbk;
    #pragma unroll
    for(int m=32;m>=1;m>>=1) c += __shfl_xor(c, m);
    if(lane == 0) part[i][wid] = c;
  }
  __syncthreads();
  if(tid < BB){
    float acc = bbv;
    #pragma unroll
    for(int wq=0; wq<8; wq++) acc += part[tid][wq];
    beta[b0+tid] = acc;
  }
}

// k_fused: one block per batch b. Stage v[b] (49x512) as swizzled bf16 in LDS
// (chunk-pipelined with the GEMM), MFMA vproj with frag-packed Wv from L2,
// z = sum wz*tanh(vproj+hpb), softmax(z,beta) in-block, then c = a·v from LDS.
__global__ __launch_bounds__(256, 3) void k_fused(
    const float* __restrict__ v, const ushort_* __restrict__ bpack,
    const float* __restrict__ hpb, const float* __restrict__ wz,
    const float* __restrict__ bz_p, const float* __restrict__ beta,
    const float* __restrict__ s, float* __restrict__ out)
{
  __shared__ __align__(16) ushort_ Av[49*512];   // 50KB bf16, swizzled granules
  __shared__ float zw[4][64];
  __shared__ float a_s[64];
  const int tid = threadIdx.x;
  const int w = tid >> 6, lane = tid & 63;
  const int l15 = lane & 15, l4 = lane >> 4;
  const int b = blockIdx.x;

  const float4* __restrict__ vsrc = (const float4*)(v + (size_t)b * T_ * H_);
  const bf16x8* __restrict__ bp = (const bf16x8*)bpack;
  const int bbase = w*512 + lane;           // + kk*2048 + ni*64

  // staging map: thread covers rows {srow, srow+16, srow+32} (+row 48 if tid<16)
  const int srow = tid >> 4, c4 = tid & 15;
  const int slot = ((c4 >> 1) ^ (srow & 7));           // row&7 == srow&7 for all passes
  const int wsub = ((c4 & 1) << 3);

  // ---- prologue: stage chunk 0 (cols 0..63)
  {
    float4 nf0 = vsrc[(srow      )*128 + c4];
    float4 nf1 = vsrc[(srow + 16 )*128 + c4];
    float4 nf2 = vsrc[(srow + 32 )*128 + c4];
    float4 nf3;
    if(tid < 16) nf3 = vsrc[48*128 + c4];
    ushort4 u;
    u.x=f2bf(nf0.x); u.y=f2bf(nf0.y); u.z=f2bf(nf0.z); u.w=f2bf(nf0.w);
    *(ushort4*)((char*)Av + (srow   )*1024 + (slot<<4) + wsub) = u;
    u.x=f2bf(nf1.x); u.y=f2bf(nf1.y); u.z=f2bf(nf1.z); u.w=f2bf(nf1.w);
    *(ushort4*)((char*)Av + (srow+16)*1024 + (slot<<4) + wsub) = u;
    u.x=f2bf(nf2.x); u.y=f2bf(nf2.y); u.z=f2bf(nf2.z); u.w=f2bf(nf2.w);
    *(ushort4*)((char*)Av + (srow+32)*1024 + (slot<<4) + wsub) = u;
    if(tid < 16){
      u.x=f2bf(nf3.x); u.y=f2bf(nf3.y); u.z=f2bf(nf3.z); u.w=f2bf(nf3.w);
      *(ushort4*)((char*)Av + 48*1024 + (slot<<4) + wsub) = u;
    }
  }

  f32x4 acc[4][8];
  #pragma unroll
  for(int mi=0;mi<4;mi++)
    #pragma unroll
    for(int ni=0;ni<8;ni++) acc[mi][ni] = (f32x4){0.f,0.f,0.f,0.f};

  __syncthreads();

  // ---- main loop: 8 chunks of 64 cols (two K=32 MFMA steps each)
  #pragma unroll 1
  for(int c=0;c<8;c++){
    // 1) B-frags for both K-steps (L2-resident, issued FIRST so MFMA's vmcnt
    //    wait does not cover the HBM loads issued after them)
    bf16x8 b0[8], b1[8];
    #pragma unroll
    for(int ni=0;ni<8;ni++) b0[ni] = bp[(2*c  )*2048 + bbase + ni*64];
    #pragma unroll
    for(int ni=0;ni<8;ni++) b1[ni] = bp[(2*c+1)*2048 + bbase + ni*64];
    // 2) next chunk's v loads (HBM, long latency — land during MFMA)
    float4 nf0, nf1, nf2, nf3;
    if(c < 7){
      nf0 = vsrc[(srow      )*128 + (c+1)*16 + c4];
      nf1 = vsrc[(srow + 16 )*128 + (c+1)*16 + c4];
      nf2 = vsrc[(srow + 32 )*128 + (c+1)*16 + c4];
      if(tid < 16) nf3 = vsrc[48*128 + (c+1)*16 + c4];
    }
    // 3) compute K-step 0 (kk=2c)
    bf16x8 af[4];
    #pragma unroll
    for(int mi=0;mi<4;mi++){
      int row = (mi < 3) ? (mi*16 + l15) : 48;         // mi=3 clamps to row 48 (broadcast)
      int g   = ((2*c)*4 + l4) ^ (row & 7);
      af[mi] = *(const bf16x8*)((const char*)Av + row*1024 + (g<<4));
    }
    #pragma unroll
    for(int mi=0;mi<4;mi++)
      #pragma unroll
      for(int ni=0;ni<8;ni++)
        acc[mi][ni] = __builtin_amdgcn_mfma_f32_16x16x32_bf16(af[mi], b0[ni], acc[mi][ni], 0,0,0);
    // 4) compute K-step 1 (kk=2c+1)
    #pragma unroll
    for(int mi=0;mi<4;mi++){
      int row = (mi < 3) ? (mi*16 + l15) : 48;
      int g   = ((2*c+1)*4 + l4) ^ (row & 7);
      af[mi] = *(const bf16x8*)((const char*)Av + row*1024 + (g<<4));
    }
    #pragma unroll
    for(int mi=0;mi<4;mi++)
      #pragma unroll
      for(int ni=0;ni<8;ni++)
        acc[mi][ni] = __builtin_amdgcn_mfma_f32_16x16x32_bf16(af[mi], b1[ni], acc[mi][ni], 0,0,0);
    // 5) write staged chunk (waits only the v loads; they had the MFMA phase)
    if(c < 7){
      const int cb = (c+1)*128;
      ushort4 u;
      u.x=f2bf(nf0.x); u.y=f2bf(nf0.y); u.z=f2bf(nf0.z); u.w=f2bf(nf0.w);
      *(ushort4*)((char*)Av + (srow   )*1024 + cb + (slot<<4) + wsub) = u;
      u.x=f2bf(nf1.x); u.y=f2bf(nf1.y); u.z=f2bf(nf1.z); u.w=f2bf(nf1.w);
      *(ushort4*)((char*)Av + (srow+16)*1024 + cb + (slot<<4) + wsub) = u;
      u.x=f2bf(nf2.x); u.y=f2bf(nf2.y); u.z=f2bf(nf2.z); u.w=f2bf(nf2.w);
      *(ushort4*)((char*)Av + (srow+32)*1024 + cb + (slot<<4) + wsub) = u;
      if(tid < 16){
        u.x=f2bf(nf3.x); u.y=f2bf(nf3.y); u.z=f2bf(nf3.z); u.w=f2bf(nf3.w);
        *(ushort4*)((char*)Av + 48*1024 + cb + (slot<<4) + wsub) = u;
      }
    }
    __syncthreads();
  }

  // ---- z partials: z[t] = sum_n wz[n]*tanh(acc + hpb[b][n]) + bz
  float wzv[8], hp0[8];
  #pragma unroll
  for(int ni=0;ni<8;ni++){
    int col = w*128 + ni*16 + l15;
    wzv[ni] = wz[col];
    hp0[ni] = hpb[(size_t)b*H_ + col];
  }
  float zp[16];
  #pragma unroll
  for(int mi=0;mi<4;mi++){
    #pragma unroll
    for(int r=0;r<4;r++){
      float az = 0.f;
      #pragma unroll
      for(int ni=0;ni<8;ni++)
        az = fmaf(fast_tanh(acc[mi][ni][r] + hp0[ni]), wzv[ni], az);
      zp[mi*4+r] = az;
    }
  }
  #pragma unroll
  for(int i=0;i<16;i++){
    zp[i] += __shfl_xor(zp[i], 1);
    zp[i] += __shfl_xor(zp[i], 2);
    zp[i] += __shfl_xor(zp[i], 4);
    zp[i] += __shfl_xor(zp[i], 8);
  }
  if(l15 == 0){
    #pragma unroll
    for(int mi=0;mi<4;mi++)
      #pragma unroll
      for(int r=0;r<4;r++)
        zw[w][mi*16 + l4*4 + r] = zp[mi*4+r];
  }
  __syncthreads();

  // ---- softmax over [z(49), beta] (wave 0)
  if(tid < 64){
    float zv;
    if(tid < T_)       zv = zw[0][tid] + zw[1][tid] + zw[2][tid] + zw[3][tid] + bz_p[0];
    else if(tid == T_) zv = beta[b];
    else               zv = -3.0e38f;
    float m = zv;
    #pragma unroll
    for(int off=32;off>=1;off>>=1) m = fmaxf(m, __shfl_xor(m, off));
    float e = (tid <= T_) ? __expf(zv - m) : 0.f;
    float ssum = e;
    #pragma unroll
    for(int off=32;off>=1;off>>=1) ssum += __shfl_xor(ssum, off);
    a_s[tid] = e * __builtin_amdgcn_rcpf(ssum);
  }
  __syncthreads();

  // ---- PV: c[n] = sum_t a[t]*v_bf16[t][n] + a[49]*s[b][n]; 2 cols/thread
  const int n0 = tid * 2;
  float ax = 0.f, ay = 0.f;
  #pragma unroll 7
  for(int t=0;t<T_;t++){
    float at = a_s[t];
    unsigned int u = *(const unsigned int*)((const char*)Av + t*1024
                       + ((((n0>>3) ^ (t&7)))<<4) + ((n0&7)<<1));
    float x = __uint_as_float((u & 0xFFFFu) << 16);
    float y = __uint_as_float(u & 0xFFFF0000u);
    ax = fmaf(at, x, ax);
    ay = fmaf(at, y, ay);
  }
  float a49 = a_s[T_];
  float2 sv = ((const float2*)(s + (size_t)b*H_))[tid];
  ax = fmaf(a49, sv.x, ax);
  ay = fmaf(a49, sv.y, ay);
  float2 res; res.x = ax; res.y = ay;
  ((float2*)(out + (size_t)b*H_))[tid] = res;
}

extern "C" void kernel_launch(void* const* d_in, const int* in_sizes, int n_in,
                              void* d_out, int out_size, void* d_ws, size_t ws_size,
                              hipStream_t stream)
{
  const float* v   = (const float*)d_in[0];
  const float* h   = (const float*)d_in[1];
  const float* s   = (const float*)d_in[2];
  const float* Wh  = (const float*)d_in[3];
  const float* bh  = (const float*)d_in[4];
  const float* Wv  = (const float*)d_in[5];
  const float* bv  = (const float*)d_in[6];
  const float* wz  = (const float*)d_in[7];
  const float* bz  = (const float*)d_in[8];
  const float* Ws  = (const float*)d_in[9];
  const float* bs  = (const float*)d_in[10];
  const float* wb  = (const float*)d_in[11];
  const float* bbet= (const float*)d_in[12];
  float* out = (float*)d_out;

  // workspace: hpb (8MB) + beta + bpack (512KB)
  float* hpb  = (float*)d_ws;                      // B*H f32
  float* beta = hpb + (size_t)B_*H_;               // B f32
  ushort_* bpack = (ushort_*)(beta + B_);          // frag-packed bf16 Wv

  k_pack <<<128, 256, 0, stream>>>(Wv, bpack);
  k_proj <<<B_/BB, 512, 0, stream>>>(h, s, Wh, bh, Ws, bs, bv, wb, bbet, hpb, beta);
  k_fused<<<B_, 256, 0, stream>>>(v, bpack, hpb, wz, bz, beta, s, out);
}

// Round 4
// 266.385 us; speedup vs baseline: 4.6165x; 4.6165x over previous
//
#include <hip/hip_runtime.h>
#include <stdint.h>

#define B_ 4096
#define T_ 49
#define H_ 512
#define BT_ (B_*T_)
#define BB 16

typedef __bf16 bf16x8 __attribute__((ext_vector_type(8)));
typedef float  f32x4  __attribute__((ext_vector_type(4)));
typedef unsigned short ushort_;

__device__ __forceinline__ ushort_ f2bf(float f){
  unsigned int u = __float_as_uint(f);
  u += 0x7fffu + ((u >> 16) & 1u);           // RNE
  return (ushort_)(u >> 16);
}

__device__ __forceinline__ float fast_tanh(float x){
  float e = __expf(2.0f * x);
  return 1.0f - 2.0f * __builtin_amdgcn_rcpf(e + 1.0f);
}

// k_pack: Wv [K][N] f32 -> fragment-ordered bf16.
// bpack[((kk*32 + gt)*64 + lane)*8 + e] = bf16(Wv[kk*32 + (lane>>4)*8 + e][gt*16 + (lane&15)])
__global__ __launch_bounds__(256) void k_pack(const float* __restrict__ Wv,
                                              ushort_* __restrict__ bpack){
  int idx = blockIdx.x * 256 + threadIdx.x;   // 0..32767
  int lane = idx & 63;
  int gt   = (idx >> 6) & 31;
  int kk   = idx >> 11;
  int col  = gt*16 + (lane & 15);
  int k0   = kk*32 + (lane >> 4)*8;
  ushort4 lo, hi;
  lo.x = f2bf(Wv[(k0+0)*H_ + col]);
  lo.y = f2bf(Wv[(k0+1)*H_ + col]);
  lo.z = f2bf(Wv[(k0+2)*H_ + col]);
  lo.w = f2bf(Wv[(k0+3)*H_ + col]);
  hi.x = f2bf(Wv[(k0+4)*H_ + col]);
  hi.y = f2bf(Wv[(k0+5)*H_ + col]);
  hi.z = f2bf(Wv[(k0+6)*H_ + col]);
  hi.w = f2bf(Wv[(k0+7)*H_ + col]);
  ushort4* dst = (ushort4*)bpack;
  dst[idx*2]   = lo;
  dst[idx*2+1] = hi;
}

// K1: hpb[b][k] = h@W_h + b_h + b_v ; beta[b] = tanh((s@W_s + b_s + h_proj)*sqrt(.5))@w_beta + b_beta
__global__ __launch_bounds__(512) void k_proj(
    const float* __restrict__ h, const float* __restrict__ s,
    const float* __restrict__ Wh, const float* __restrict__ bh,
    const float* __restrict__ Ws, const float* __restrict__ bs,
    const float* __restrict__ bv, const float* __restrict__ wbeta,
    const float* __restrict__ bbeta_p,
    float* __restrict__ hpb, float* __restrict__ beta)
{
  __shared__ float hs[H_*BB];     // [j][bb] layout
  __shared__ float ssm[H_*BB];
  __shared__ float part[BB][8];
  const int tid = threadIdx.x;
  const int b0 = blockIdx.x * BB;

  for(int idx = tid; idx < H_*BB; idx += 512){
    int bb2 = idx & (BB-1);
    int j   = idx >> 4;
    hs[idx]  = h[(size_t)(b0+bb2)*H_ + j];
    ssm[idx] = s[(size_t)(b0+bb2)*H_ + j];
  }
  __syncthreads();

  const int k = tid;
  float ah[BB], as_[BB];
  #pragma unroll
  for(int i=0;i<BB;i++){ ah[i]=0.f; as_[i]=0.f; }

  #pragma unroll 4
  for(int j=0;j<H_;j++){
    float whv = Wh[j*H_ + k];
    float wsv = Ws[j*H_ + k];
    #pragma unroll
    for(int i=0;i<BB;i++){
      ah[i]  = fmaf(hs[j*BB+i],  whv, ah[i]);
      as_[i] = fmaf(ssm[j*BB+i], wsv, as_[i]);
    }
  }

  const float bhk = bh[k], bsk = bs[k], bvk = bv[k], wbk = wbeta[k];
  const float bbv = bbeta_p[0];
  const int lane = tid & 63, wid = tid >> 6;

  #pragma unroll
  for(int i=0;i<BB;i++){
    float hp = ah[i] + bhk;
    hpb[(size_t)(b0+i)*H_ + k] = hp + bvk;
    float bt = fast_tanh((as_[i] + bsk + hp) * 0.70710678118654752f);
    float c = bt * wbk;
    #pragma unroll
    for(int m=32;m>=1;m>>=1) c += __shfl_xor(c, m);
    if(lane == 0) part[i][wid] = c;
  }
  __syncthreads();
  if(tid < BB){
    float acc = bbv;
    #pragma unroll
    for(int wq=0; wq<8; wq++) acc += part[tid][wq];
    beta[b0+tid] = acc;
  }
}

// k_fused: one block per batch b. Stage v[b] (49x512) as swizzled bf16 in LDS
// (chunk-pipelined with the GEMM), MFMA vproj with frag-packed Wv from L2,
// z = sum wz*tanh(vproj+hpb), softmax(z,beta) in-block, then c = a·v from LDS.
// launch_bounds(256,2): 256-reg unified budget -> NO spill (r3 lesson: (256,3)
// capped at ~170 and spilled ~2.5GB of scratch per dispatch).
__global__ __launch_bounds__(256, 2) void k_fused(
    const float* __restrict__ v, const ushort_* __restrict__ bpack,
    const float* __restrict__ hpb, const float* __restrict__ wz,
    const float* __restrict__ bz_p, const float* __restrict__ beta,
    const float* __restrict__ s, float* __restrict__ out)
{
  __shared__ __align__(16) ushort_ Av[49*512];   // 50KB bf16, swizzled granules
  __shared__ float zw[4][64];
  __shared__ float a_s[64];
  const int tid = threadIdx.x;
  const int w = tid >> 6, lane = tid & 63;
  const int l15 = lane & 15, l4 = lane >> 4;
  const int b = blockIdx.x;

  const f32x4* __restrict__ vsrc = (const f32x4*)(v + (size_t)b * T_ * H_);
  const bf16x8* __restrict__ bp = (const bf16x8*)bpack;
  const int bbase = w*512 + lane;           // + kk*2048 + ni*64

  // staging map: thread covers rows {srow, srow+16, srow+32} (+row 48 if tid<16)
  const int srow = tid >> 4, c4 = tid & 15;
  const int slot = ((c4 >> 1) ^ (srow & 7));           // row&7 == srow&7 for all passes
  const int wsub = ((c4 & 1) << 3);

  // ---- prologue: stage chunk 0 (cols 0..63); v is single-use -> non-temporal
  {
    f32x4 nf0 = __builtin_nontemporal_load(vsrc + (srow      )*128 + c4);
    f32x4 nf1 = __builtin_nontemporal_load(vsrc + (srow + 16 )*128 + c4);
    f32x4 nf2 = __builtin_nontemporal_load(vsrc + (srow + 32 )*128 + c4);
    f32x4 nf3;
    if(tid < 16) nf3 = __builtin_nontemporal_load(vsrc + 48*128 + c4);
    ushort4 u;
    u.x=f2bf(nf0[0]); u.y=f2bf(nf0[1]); u.z=f2bf(nf0[2]); u.w=f2bf(nf0[3]);
    *(ushort4*)((char*)Av + (srow   )*1024 + (slot<<4) + wsub) = u;
    u.x=f2bf(nf1[0]); u.y=f2bf(nf1[1]); u.z=f2bf(nf1[2]); u.w=f2bf(nf1[3]);
    *(ushort4*)((char*)Av + (srow+16)*1024 + (slot<<4) + wsub) = u;
    u.x=f2bf(nf2[0]); u.y=f2bf(nf2[1]); u.z=f2bf(nf2[2]); u.w=f2bf(nf2[3]);
    *(ushort4*)((char*)Av + (srow+32)*1024 + (slot<<4) + wsub) = u;
    if(tid < 16){
      u.x=f2bf(nf3[0]); u.y=f2bf(nf3[1]); u.z=f2bf(nf3[2]); u.w=f2bf(nf3[3]);
      *(ushort4*)((char*)Av + 48*1024 + (slot<<4) + wsub) = u;
    }
  }

  f32x4 acc[4][8];
  #pragma unroll
  for(int mi=0;mi<4;mi++)
    #pragma unroll
    for(int ni=0;ni<8;ni++) acc[mi][ni] = (f32x4){0.f,0.f,0.f,0.f};

  __syncthreads();

  // ---- main loop: 8 chunks of 64 cols (two K=32 MFMA steps each)
  #pragma unroll 1
  for(int c=0;c<8;c++){
    // 1) B-frags for both K-steps (L2-resident, issued FIRST: in-order vmcnt
    //    means MFMA's wait must not cover the HBM v-loads)
    bf16x8 b0[8], b1[8];
    #pragma unroll
    for(int ni=0;ni<8;ni++) b0[ni] = bp[(2*c  )*2048 + bbase + ni*64];
    #pragma unroll
    for(int ni=0;ni<8;ni++) b1[ni] = bp[(2*c+1)*2048 + bbase + ni*64];
    // 2) next chunk's v loads (HBM, long latency — land during MFMA)
    f32x4 nf0, nf1, nf2, nf3;
    if(c < 7){
      nf0 = __builtin_nontemporal_load(vsrc + (srow      )*128 + (c+1)*16 + c4);
      nf1 = __builtin_nontemporal_load(vsrc + (srow + 16 )*128 + (c+1)*16 + c4);
      nf2 = __builtin_nontemporal_load(vsrc + (srow + 32 )*128 + (c+1)*16 + c4);
      if(tid < 16) nf3 = __builtin_nontemporal_load(vsrc + 48*128 + (c+1)*16 + c4);
    }
    // 3) compute K-step 0 (kk=2c)
    bf16x8 af[4];
    #pragma unroll
    for(int mi=0;mi<4;mi++){
      int row = (mi < 3) ? (mi*16 + l15) : 48;         // mi=3 clamps to row 48 (broadcast)
      int g   = ((2*c)*4 + l4) ^ (row & 7);
      af[mi] = *(const bf16x8*)((const char*)Av + row*1024 + (g<<4));
    }
    #pragma unroll
    for(int mi=0;mi<4;mi++)
      #pragma unroll
      for(int ni=0;ni<8;ni++)
        acc[mi][ni] = __builtin_amdgcn_mfma_f32_16x16x32_bf16(af[mi], b0[ni], acc[mi][ni], 0,0,0);
    // 4) compute K-step 1 (kk=2c+1)
    #pragma unroll
    for(int mi=0;mi<4;mi++){
      int row = (mi < 3) ? (mi*16 + l15) : 48;
      int g   = ((2*c+1)*4 + l4) ^ (row & 7);
      af[mi] = *(const bf16x8*)((const char*)Av + row*1024 + (g<<4));
    }
    #pragma unroll
    for(int mi=0;mi<4;mi++)
      #pragma unroll
      for(int ni=0;ni<8;ni++)
        acc[mi][ni] = __builtin_amdgcn_mfma_f32_16x16x32_bf16(af[mi], b1[ni], acc[mi][ni], 0,0,0);
    // 5) write staged chunk (waits only the v loads; they had the MFMA phase)
    if(c < 7){
      const int cb = (c+1)*128;
      ushort4 u;
      u.x=f2bf(nf0[0]); u.y=f2bf(nf0[1]); u.z=f2bf(nf0[2]); u.w=f2bf(nf0[3]);
      *(ushort4*)((char*)Av + (srow   )*1024 + cb + (slot<<4) + wsub) = u;
      u.x=f2bf(nf1[0]); u.y=f2bf(nf1[1]); u.z=f2bf(nf1[2]); u.w=f2bf(nf1[3]);
      *(ushort4*)((char*)Av + (srow+16)*1024 + cb + (slot<<4) + wsub) = u;
      u.x=f2bf(nf2[0]); u.y=f2bf(nf2[1]); u.z=f2bf(nf2[2]); u.w=f2bf(nf2[3]);
      *(ushort4*)((char*)Av + (srow+32)*1024 + cb + (slot<<4) + wsub) = u;
      if(tid < 16){
        u.x=f2bf(nf3[0]); u.y=f2bf(nf3[1]); u.z=f2bf(nf3[2]); u.w=f2bf(nf3[3]);
        *(ushort4*)((char*)Av + 48*1024 + cb + (slot<<4) + wsub) = u;
      }
    }
    __syncthreads();
  }

  // ---- z partials: z[t] = sum_n wz[n]*tanh(acc + hpb[b][n]) + bz
  float wzv[8], hp0[8];
  #pragma unroll
  for(int ni=0;ni<8;ni++){
    int col = w*128 + ni*16 + l15;
    wzv[ni] = wz[col];
    hp0[ni] = hpb[(size_t)b*H_ + col];
  }
  float zp[16];
  #pragma unroll
  for(int mi=0;mi<4;mi++){
    #pragma unroll
    for(int r=0;r<4;r++){
      float az = 0.f;
      #pragma unroll
      for(int ni=0;ni<8;ni++)
        az = fmaf(fast_tanh(acc[mi][ni][r] + hp0[ni]), wzv[ni], az);
      zp[mi*4+r] = az;
    }
  }
  #pragma unroll
  for(int i=0;i<16;i++){
    zp[i] += __shfl_xor(zp[i], 1);
    zp[i] += __shfl_xor(zp[i], 2);
    zp[i] += __shfl_xor(zp[i], 4);
    zp[i] += __shfl_xor(zp[i], 8);
  }
  if(l15 == 0){
    #pragma unroll
    for(int mi=0;mi<4;mi++)
      #pragma unroll
      for(int r=0;r<4;r++)
        zw[w][mi*16 + l4*4 + r] = zp[mi*4+r];
  }
  __syncthreads();

  // ---- softmax over [z(49), beta] (wave 0)
  if(tid < 64){
    float zv;
    if(tid < T_)       zv = zw[0][tid] + zw[1][tid] + zw[2][tid] + zw[3][tid] + bz_p[0];
    else if(tid == T_) zv = beta[b];
    else               zv = -3.0e38f;
    float m = zv;
    #pragma unroll
    for(int off=32;off>=1;off>>=1) m = fmaxf(m, __shfl_xor(m, off));
    float e = (tid <= T_) ? __expf(zv - m) : 0.f;
    float ssum = e;
    #pragma unroll
    for(int off=32;off>=1;off>>=1) ssum += __shfl_xor(ssum, off);
    a_s[tid] = e * __builtin_amdgcn_rcpf(ssum);
  }
  __syncthreads();

  // ---- PV: c[n] = sum_t a[t]*v_bf16[t][n] + a[49]*s[b][n]; 2 cols/thread
  const int n0 = tid * 2;
  float ax = 0.f, ay = 0.f;
  #pragma unroll 7
  for(int t=0;t<T_;t++){
    float at = a_s[t];
    unsigned int u = *(const unsigned int*)((const char*)Av + t*1024
                       + ((((n0>>3) ^ (t&7)))<<4) + ((n0&7)<<1));
    float x = __uint_as_float((u & 0xFFFFu) << 16);
    float y = __uint_as_float(u & 0xFFFF0000u);
    ax = fmaf(at, x, ax);
    ay = fmaf(at, y, ay);
  }
  float a49 = a_s[T_];
  float2 sv = ((const float2*)(s + (size_t)b*H_))[tid];
  ax = fmaf(a49, sv.x, ax);
  ay = fmaf(a49, sv.y, ay);
  float2 res; res.x = ax; res.y = ay;
  ((float2*)(out + (size_t)b*H_))[tid] = res;
}

extern "C" void kernel_launch(void* const* d_in, const int* in_sizes, int n_in,
                              void* d_out, int out_size, void* d_ws, size_t ws_size,
                              hipStream_t stream)
{
  const float* v   = (const float*)d_in[0];
  const float* h   = (const float*)d_in[1];
  const float* s   = (const float*)d_in[2];
  const float* Wh  = (const float*)d_in[3];
  const float* bh  = (const float*)d_in[4];
  const float* Wv  = (const float*)d_in[5];
  const float* bv  = (const float*)d_in[6];
  const float* wz  = (const float*)d_in[7];
  const float* bz  = (const float*)d_in[8];
  const float* Ws  = (const float*)d_in[9];
  const float* bs  = (const float*)d_in[10];
  const float* wb  = (const float*)d_in[11];
  const float* bbet= (const float*)d_in[12];
  float* out = (float*)d_out;

  // workspace: hpb (8MB) + beta + bpack (512KB)
  float* hpb  = (float*)d_ws;                      // B*H f32
  float* beta = hpb + (size_t)B_*H_;               // B f32
  ushort_* bpack = (ushort_*)(beta + B_);          // frag-packed bf16 Wv

  k_pack <<<128, 256, 0, stream>>>(Wv, bpack);
  k_proj <<<B_/BB, 512, 0, stream>>>(h, s, Wh, bh, Ws, bs, bv, wb, bbet, hpb, beta);
  k_fused<<<B_, 256, 0, stream>>>(v, bpack, hpb, wz, bz, beta, s, out);
}

// Round 5
// 217.185 us; speedup vs baseline: 5.6624x; 1.2265x over previous
//
#include <hip/hip_runtime.h>
#include <stdint.h>

#define B_ 4096
#define T_ 49
#define H_ 512
#define BT_ (B_*T_)
#define BB 16

typedef __bf16 bf16x8 __attribute__((ext_vector_type(8)));
typedef float  f32x4  __attribute__((ext_vector_type(4)));
typedef unsigned short ushort_;

__device__ __forceinline__ ushort_ f2bf(float f){
  unsigned int u = __float_as_uint(f);
  u += 0x7fffu + ((u >> 16) & 1u);           // RNE
  return (ushort_)(u >> 16);
}

__device__ __forceinline__ float fast_tanh(float x){
  float e = __expf(2.0f * x);
  return 1.0f - 2.0f * __builtin_amdgcn_rcpf(e + 1.0f);
}

// k_pack: W [K][N] f32 -> fragment-ordered bf16.
// pack[((kk*32 + gt)*64 + lane)*8 + e] = bf16(W[kk*32 + (lane>>4)*8 + e][gt*16 + (lane&15)])
__global__ __launch_bounds__(256) void k_pack(const float* __restrict__ W,
                                              ushort_* __restrict__ pack){
  int idx = blockIdx.x * 256 + threadIdx.x;   // 0..32767
  int lane = idx & 63;
  int gt   = (idx >> 6) & 31;
  int kk   = idx >> 11;
  int col  = gt*16 + (lane & 15);
  int k0   = kk*32 + (lane >> 4)*8;
  ushort4 lo, hi;
  lo.x = f2bf(W[(k0+0)*H_ + col]);
  lo.y = f2bf(W[(k0+1)*H_ + col]);
  lo.z = f2bf(W[(k0+2)*H_ + col]);
  lo.w = f2bf(W[(k0+3)*H_ + col]);
  hi.x = f2bf(W[(k0+4)*H_ + col]);
  hi.y = f2bf(W[(k0+5)*H_ + col]);
  hi.z = f2bf(W[(k0+6)*H_ + col]);
  hi.w = f2bf(W[(k0+7)*H_ + col]);
  ushort4* dst = (ushort4*)pack;
  dst[idx*2]   = lo;
  dst[idx*2+1] = hi;
}

// k_proj2 (MFMA): 16 batches/block, 256 threads. Both h@W_h and s@W_s GEMMs
// via 16x16x32 bf16 MFMA; B-frags from frag-packed whp/wsp (L2), A staged in
// LDS in frag order. Epilogue: hpb = h_proj + b_v ; beta scalar.
__global__ __launch_bounds__(256) void k_proj2(
    const float* __restrict__ h, const float* __restrict__ s,
    const ushort_* __restrict__ whp, const ushort_* __restrict__ wsp,
    const float* __restrict__ bh, const float* __restrict__ bs,
    const float* __restrict__ bv, const float* __restrict__ wbeta,
    const float* __restrict__ bbeta_p,
    float* __restrict__ hpb, float* __restrict__ beta)
{
  __shared__ __align__(16) ushort_ hl[16*H_];   // 16KB, A-frag order
  __shared__ __align__(16) ushort_ sl[16*H_];
  __shared__ float zwp[4][16];
  const int tid = threadIdx.x;
  const int w = tid >> 6, lane = tid & 63;
  const int l15 = lane & 15, l4 = lane >> 4;
  const int b0 = blockIdx.x * 16;

  // stage h,s -> frag layout: elem(row r, k) at [(k>>5)*512 + (((k&31)>>3)*16 + r)*8 + (k&7)]
  {
    const int r = tid >> 4;
    const float4* hsrc = (const float4*)(h + (size_t)(b0+r)*H_);
    const float4* ssrc = (const float4*)(s + (size_t)(b0+r)*H_);
    #pragma unroll
    for(int p=0;p<8;p++){
      int q  = (tid & 15) + p*16;         // float4 col
      int k0 = q*4;
      float4 fh = hsrc[q];
      float4 fs = ssrc[q];
      int idx = (k0>>5)*512 + ((((k0&31)>>3)<<4) + r)*8 + (k0&7);
      ushort4 uh; uh.x=f2bf(fh.x); uh.y=f2bf(fh.y); uh.z=f2bf(fh.z); uh.w=f2bf(fh.w);
      ushort4 us; us.x=f2bf(fs.x); us.y=f2bf(fs.y); us.z=f2bf(fs.z); us.w=f2bf(fs.w);
      *(ushort4*)&hl[idx] = uh;
      *(ushort4*)&sl[idx] = us;
    }
  }
  __syncthreads();

  const bf16x8* __restrict__ bph = (const bf16x8*)whp;
  const bf16x8* __restrict__ bps = (const bf16x8*)wsp;
  const int bbase = w*512 + lane;

  f32x4 acch[8], accs[8];
  #pragma unroll
  for(int ni=0;ni<8;ni++){ acch[ni]=(f32x4){0,0,0,0}; accs[ni]=(f32x4){0,0,0,0}; }

  #pragma unroll 2
  for(int kk=0;kk<16;kk++){
    bf16x8 ah = *(const bf16x8*)&hl[kk*512 + lane*8];
    bf16x8 as2 = *(const bf16x8*)&sl[kk*512 + lane*8];
    #pragma unroll
    for(int ni=0;ni<8;ni++){
      acch[ni] = __builtin_amdgcn_mfma_f32_16x16x32_bf16(ah,  bph[kk*2048 + bbase + ni*64], acch[ni], 0,0,0);
      accs[ni] = __builtin_amdgcn_mfma_f32_16x16x32_bf16(as2, bps[kk*2048 + bbase + ni*64], accs[ni], 0,0,0);
    }
  }

  // epilogue: C row = l4*4+r (batch idx in block), col = w*128 + ni*16 + l15
  float bhv[8], bsv[8], bvv[8], wbv[8];
  #pragma unroll
  for(int ni=0;ni<8;ni++){
    int col = w*128 + ni*16 + l15;
    bhv[ni] = bh[col]; bsv[ni] = bs[col]; bvv[ni] = bv[col]; wbv[ni] = wbeta[col];
  }
  float btsum[4];
  #pragma unroll
  for(int rr=0;rr<4;rr++){
    int row = l4*4 + rr;
    float bsum = 0.f;
    #pragma unroll
    for(int ni=0;ni<8;ni++){
      int col = w*128 + ni*16 + l15;
      float hp = acch[ni][rr] + bhv[ni];
      hpb[(size_t)(b0+row)*H_ + col] = hp + bvv[ni];
      float bt = fast_tanh((accs[ni][rr] + bsv[ni] + hp) * 0.70710678118654752f);
      bsum = fmaf(bt, wbv[ni], bsum);
    }
    btsum[rr] = bsum;
  }
  #pragma unroll
  for(int rr=0;rr<4;rr++){
    btsum[rr] += __shfl_xor(btsum[rr], 1);
    btsum[rr] += __shfl_xor(btsum[rr], 2);
    btsum[rr] += __shfl_xor(btsum[rr], 4);
    btsum[rr] += __shfl_xor(btsum[rr], 8);
    if(l15 == 0) zwp[w][l4*4+rr] = btsum[rr];
  }
  __syncthreads();
  if(tid < 16)
    beta[b0+tid] = zwp[0][tid] + zwp[1][tid] + zwp[2][tid] + zwp[3][tid] + bbeta_p[0];
}

// k_fused: one block per batch b. Stage v[b] (49x512) as swizzled bf16 in LDS
// (chunk-pipelined with the GEMM), MFMA vproj with frag-packed Wv from L2,
// z = sum wz*tanh(vproj+hpb), softmax(z,beta) in-block, then c = a·v from LDS.
// launch_bounds(256,2): 256-reg unified budget -> NO spill (r3 lesson).
__global__ __launch_bounds__(256, 2) void k_fused(
    const float* __restrict__ v, const ushort_* __restrict__ bpack,
    const float* __restrict__ hpb, const float* __restrict__ wz,
    const float* __restrict__ bz_p, const float* __restrict__ beta,
    const float* __restrict__ s, float* __restrict__ out)
{
  __shared__ __align__(16) ushort_ Av[49*512];   // 50KB bf16, swizzled granules
  __shared__ float zw[4][64];
  __shared__ float a_s[64];
  const int tid = threadIdx.x;
  const int w = tid >> 6, lane = tid & 63;
  const int l15 = lane & 15, l4 = lane >> 4;
  const int b = blockIdx.x;

  const f32x4* __restrict__ vsrc = (const f32x4*)(v + (size_t)b * T_ * H_);
  const bf16x8* __restrict__ bp = (const bf16x8*)bpack;
  const int bbase = w*512 + lane;           // + kk*2048 + ni*64

  // staging map: thread covers rows {srow, srow+16, srow+32} (+row 48 if tid<16)
  const int srow = tid >> 4, c4 = tid & 15;
  const int slot = ((c4 >> 1) ^ (srow & 7));           // row&7 == srow&7 for all passes
  const int wsub = ((c4 & 1) << 3);

  // ---- prologue: stage chunk 0 (cols 0..63); v is single-use -> non-temporal
  {
    f32x4 nf0 = __builtin_nontemporal_load(vsrc + (srow      )*128 + c4);
    f32x4 nf1 = __builtin_nontemporal_load(vsrc + (srow + 16 )*128 + c4);
    f32x4 nf2 = __builtin_nontemporal_load(vsrc + (srow + 32 )*128 + c4);
    f32x4 nf3;
    if(tid < 16) nf3 = __builtin_nontemporal_load(vsrc + 48*128 + c4);
    ushort4 u;
    u.x=f2bf(nf0[0]); u.y=f2bf(nf0[1]); u.z=f2bf(nf0[2]); u.w=f2bf(nf0[3]);
    *(ushort4*)((char*)Av + (srow   )*1024 + (slot<<4) + wsub) = u;
    u.x=f2bf(nf1[0]); u.y=f2bf(nf1[1]); u.z=f2bf(nf1[2]); u.w=f2bf(nf1[3]);
    *(ushort4*)((char*)Av + (srow+16)*1024 + (slot<<4) + wsub) = u;
    u.x=f2bf(nf2[0]); u.y=f2bf(nf2[1]); u.z=f2bf(nf2[2]); u.w=f2bf(nf2[3]);
    *(ushort4*)((char*)Av + (srow+32)*1024 + (slot<<4) + wsub) = u;
    if(tid < 16){
      u.x=f2bf(nf3[0]); u.y=f2bf(nf3[1]); u.z=f2bf(nf3[2]); u.w=f2bf(nf3[3]);
      *(ushort4*)((char*)Av + 48*1024 + (slot<<4) + wsub) = u;
    }
  }

  f32x4 acc[4][8];
  #pragma unroll
  for(int mi=0;mi<4;mi++)
    #pragma unroll
    for(int ni=0;ni<8;ni++) acc[mi][ni] = (f32x4){0.f,0.f,0.f,0.f};

  __syncthreads();

  // ---- main loop: 8 chunks of 64 cols (two K=32 MFMA steps each)
  #pragma unroll 1
  for(int c=0;c<8;c++){
    // 1) B-frags for both K-steps (L2-resident, issued FIRST: in-order vmcnt
    //    means MFMA's wait must not cover the HBM v-loads)
    bf16x8 b0[8], b1[8];
    #pragma unroll
    for(int ni=0;ni<8;ni++) b0[ni] = bp[(2*c  )*2048 + bbase + ni*64];
    #pragma unroll
    for(int ni=0;ni<8;ni++) b1[ni] = bp[(2*c+1)*2048 + bbase + ni*64];
    // 2) next chunk's v loads (HBM, long latency — land during MFMA)
    f32x4 nf0, nf1, nf2, nf3;
    if(c < 7){
      nf0 = __builtin_nontemporal_load(vsrc + (srow      )*128 + (c+1)*16 + c4);
      nf1 = __builtin_nontemporal_load(vsrc + (srow + 16 )*128 + (c+1)*16 + c4);
      nf2 = __builtin_nontemporal_load(vsrc + (srow + 32 )*128 + (c+1)*16 + c4);
      if(tid < 16) nf3 = __builtin_nontemporal_load(vsrc + 48*128 + (c+1)*16 + c4);
    }
    // 3) compute K-step 0 (kk=2c)
    bf16x8 af[4];
    #pragma unroll
    for(int mi=0;mi<4;mi++){
      int row = (mi < 3) ? (mi*16 + l15) : 48;         // mi=3 clamps to row 48 (broadcast)
      int g   = ((2*c)*4 + l4) ^ (row & 7);
      af[mi] = *(const bf16x8*)((const char*)Av + row*1024 + (g<<4));
    }
    #pragma unroll
    for(int mi=0;mi<4;mi++)
      #pragma unroll
      for(int ni=0;ni<8;ni++)
        acc[mi][ni] = __builtin_amdgcn_mfma_f32_16x16x32_bf16(af[mi], b0[ni], acc[mi][ni], 0,0,0);
    // 4) compute K-step 1 (kk=2c+1)
    #pragma unroll
    for(int mi=0;mi<4;mi++){
      int row = (mi < 3) ? (mi*16 + l15) : 48;
      int g   = ((2*c+1)*4 + l4) ^ (row & 7);
      af[mi] = *(const bf16x8*)((const char*)Av + row*1024 + (g<<4));
    }
    #pragma unroll
    for(int mi=0;mi<4;mi++)
      #pragma unroll
      for(int ni=0;ni<8;ni++)
        acc[mi][ni] = __builtin_amdgcn_mfma_f32_16x16x32_bf16(af[mi], b1[ni], acc[mi][ni], 0,0,0);
    // 5) write staged chunk (waits only the v loads; they had the MFMA phase)
    if(c < 7){
      const int cb = (c+1)*128;
      ushort4 u;
      u.x=f2bf(nf0[0]); u.y=f2bf(nf0[1]); u.z=f2bf(nf0[2]); u.w=f2bf(nf0[3]);
      *(ushort4*)((char*)Av + (srow   )*1024 + cb + (slot<<4) + wsub) = u;
      u.x=f2bf(nf1[0]); u.y=f2bf(nf1[1]); u.z=f2bf(nf1[2]); u.w=f2bf(nf1[3]);
      *(ushort4*)((char*)Av + (srow+16)*1024 + cb + (slot<<4) + wsub) = u;
      u.x=f2bf(nf2[0]); u.y=f2bf(nf2[1]); u.z=f2bf(nf2[2]); u.w=f2bf(nf2[3]);
      *(ushort4*)((char*)Av + (srow+32)*1024 + cb + (slot<<4) + wsub) = u;
      if(tid < 16){
        u.x=f2bf(nf3[0]); u.y=f2bf(nf3[1]); u.z=f2bf(nf3[2]); u.w=f2bf(nf3[3]);
        *(ushort4*)((char*)Av + 48*1024 + cb + (slot<<4) + wsub) = u;
      }
    }
    __syncthreads();
  }

  // ---- z partials: z[t] = sum_n wz[n]*tanh(acc + hpb[b][n]) + bz
  float wzv[8], hp0[8];
  #pragma unroll
  for(int ni=0;ni<8;ni++){
    int col = w*128 + ni*16 + l15;
    wzv[ni] = wz[col];
    hp0[ni] = hpb[(size_t)b*H_ + col];
  }
  float zp[16];
  #pragma unroll
  for(int mi=0;mi<4;mi++){
    #pragma unroll
    for(int r=0;r<4;r++){
      float az = 0.f;
      #pragma unroll
      for(int ni=0;ni<8;ni++)
        az = fmaf(fast_tanh(acc[mi][ni][r] + hp0[ni]), wzv[ni], az);
      zp[mi*4+r] = az;
    }
  }
  #pragma unroll
  for(int i=0;i<16;i++){
    zp[i] += __shfl_xor(zp[i], 1);
    zp[i] += __shfl_xor(zp[i], 2);
    zp[i] += __shfl_xor(zp[i], 4);
    zp[i] += __shfl_xor(zp[i], 8);
  }
  if(l15 == 0){
    #pragma unroll
    for(int mi=0;mi<4;mi++)
      #pragma unroll
      for(int r=0;r<4;r++)
        zw[w][mi*16 + l4*4 + r] = zp[mi*4+r];
  }
  __syncthreads();

  // ---- softmax over [z(49), beta] (wave 0)
  if(tid < 64){
    float zv;
    if(tid < T_)       zv = zw[0][tid] + zw[1][tid] + zw[2][tid] + zw[3][tid] + bz_p[0];
    else if(tid == T_) zv = beta[b];
    else               zv = -3.0e38f;
    float m = zv;
    #pragma unroll
    for(int off=32;off>=1;off>>=1) m = fmaxf(m, __shfl_xor(m, off));
    float e = (tid <= T_) ? __expf(zv - m) : 0.f;
    float ssum = e;
    #pragma unroll
    for(int off=32;off>=1;off>>=1) ssum += __shfl_xor(ssum, off);
    a_s[tid] = e * __builtin_amdgcn_rcpf(ssum);
  }
  __syncthreads();

  // ---- PV: c[n] = sum_t a[t]*v_bf16[t][n] + a[49]*s[b][n]; 2 cols/thread
  const int n0 = tid * 2;
  float ax = 0.f, ay = 0.f;
  #pragma unroll 7
  for(int t=0;t<T_;t++){
    float at = a_s[t];
    unsigned int u = *(const unsigned int*)((const char*)Av + t*1024
                       + ((((n0>>3) ^ (t&7)))<<4) + ((n0&7)<<1));
    float x = __uint_as_float((u & 0xFFFFu) << 16);
    float y = __uint_as_float(u & 0xFFFF0000u);
    ax = fmaf(at, x, ax);
    ay = fmaf(at, y, ay);
  }
  float a49 = a_s[T_];
  float2 sv = ((const float2*)(s + (size_t)b*H_))[tid];
  ax = fmaf(a49, sv.x, ax);
  ay = fmaf(a49, sv.y, ay);
  float2 res; res.x = ax; res.y = ay;
  ((float2*)(out + (size_t)b*H_))[tid] = res;
}

extern "C" void kernel_launch(void* const* d_in, const int* in_sizes, int n_in,
                              void* d_out, int out_size, void* d_ws, size_t ws_size,
                              hipStream_t stream)
{
  const float* v   = (const float*)d_in[0];
  const float* h   = (const float*)d_in[1];
  const float* s   = (const float*)d_in[2];
  const float* Wh  = (const float*)d_in[3];
  const float* bh  = (const float*)d_in[4];
  const float* Wv  = (const float*)d_in[5];
  const float* bv  = (const float*)d_in[6];
  const float* wz  = (const float*)d_in[7];
  const float* bz  = (const float*)d_in[8];
  const float* Ws  = (const float*)d_in[9];
  const float* bs  = (const float*)d_in[10];
  const float* wb  = (const float*)d_in[11];
  const float* bbet= (const float*)d_in[12];
  float* out = (float*)d_out;

  // workspace: hpb (8MB) + beta + 3 frag-packed weights (512KB each) ~= 9.6MB
  float* hpb  = (float*)d_ws;                      // B*H f32
  float* beta = hpb + (size_t)B_*H_;               // B f32
  ushort_* bpack = (ushort_*)(beta + B_);          // Wv frag-packed bf16
  ushort_* whp   = bpack + (size_t)H_*H_;          // Wh frag-packed
  ushort_* wsp   = whp   + (size_t)H_*H_;          // Ws frag-packed

  k_pack <<<128, 256, 0, stream>>>(Wv, bpack);
  k_pack <<<128, 256, 0, stream>>>(Wh, whp);
  k_pack <<<128, 256, 0, stream>>>(Ws, wsp);
  k_proj2<<<B_/16, 256, 0, stream>>>(h, s, whp, wsp, bh, bs, bv, wb, bbet, hpb, beta);
  k_fused<<<B_, 256, 0, stream>>>(v, bpack, hpb, wz, bz, beta, s, out);
}

// Round 6
// 213.506 us; speedup vs baseline: 5.7599x; 1.0172x over previous
//
#include <hip/hip_runtime.h>
#include <stdint.h>

#define B_ 4096
#define T_ 49
#define H_ 512
#define BT_ (B_*T_)
#define BB 16

typedef __bf16 bf16x8 __attribute__((ext_vector_type(8)));
typedef float  f32x4  __attribute__((ext_vector_type(4)));
typedef unsigned short ushort_;

__device__ __forceinline__ ushort_ f2bf(float f){
  unsigned int u = __float_as_uint(f);
  u += 0x7fffu + ((u >> 16) & 1u);           // RNE
  return (ushort_)(u >> 16);
}

__device__ __forceinline__ float fast_tanh(float x){
  float e = __expf(2.0f * x);
  return 1.0f - 2.0f * __builtin_amdgcn_rcpf(e + 1.0f);
}

// k_pack: W [K][N] f32 -> fragment-ordered bf16.
// pack[((kk*32 + gt)*64 + lane)*8 + e] = bf16(W[kk*32 + (lane>>4)*8 + e][gt*16 + (lane&15)])
__global__ __launch_bounds__(256) void k_pack(const float* __restrict__ W,
                                              ushort_* __restrict__ pack){
  int idx = blockIdx.x * 256 + threadIdx.x;   // 0..32767
  int lane = idx & 63;
  int gt   = (idx >> 6) & 31;
  int kk   = idx >> 11;
  int col  = gt*16 + (lane & 15);
  int k0   = kk*32 + (lane >> 4)*8;
  ushort4 lo, hi;
  lo.x = f2bf(W[(k0+0)*H_ + col]);
  lo.y = f2bf(W[(k0+1)*H_ + col]);
  lo.z = f2bf(W[(k0+2)*H_ + col]);
  lo.w = f2bf(W[(k0+3)*H_ + col]);
  hi.x = f2bf(W[(k0+4)*H_ + col]);
  hi.y = f2bf(W[(k0+5)*H_ + col]);
  hi.z = f2bf(W[(k0+6)*H_ + col]);
  hi.w = f2bf(W[(k0+7)*H_ + col]);
  ushort4* dst = (ushort4*)pack;
  dst[idx*2]   = lo;
  dst[idx*2+1] = hi;
}

// k_proj2 (MFMA): 16 batches/block; h@W_h and s@W_s; epilogue hpb & beta.
__global__ __launch_bounds__(256) void k_proj2(
    const float* __restrict__ h, const float* __restrict__ s,
    const ushort_* __restrict__ whp, const ushort_* __restrict__ wsp,
    const float* __restrict__ bh, const float* __restrict__ bs,
    const float* __restrict__ bv, const float* __restrict__ wbeta,
    const float* __restrict__ bbeta_p,
    float* __restrict__ hpb, float* __restrict__ beta)
{
  __shared__ __align__(16) ushort_ hl[16*H_];   // 16KB, A-frag order
  __shared__ __align__(16) ushort_ sl[16*H_];
  __shared__ float zwp[4][16];
  const int tid = threadIdx.x;
  const int w = tid >> 6, lane = tid & 63;
  const int l15 = lane & 15, l4 = lane >> 4;
  const int b0 = blockIdx.x * 16;

  {
    const int r = tid >> 4;
    const float4* hsrc = (const float4*)(h + (size_t)(b0+r)*H_);
    const float4* ssrc = (const float4*)(s + (size_t)(b0+r)*H_);
    #pragma unroll
    for(int p=0;p<8;p++){
      int q  = (tid & 15) + p*16;         // float4 col
      int k0 = q*4;
      float4 fh = hsrc[q];
      float4 fs = ssrc[q];
      int idx = (k0>>5)*512 + ((((k0&31)>>3)<<4) + r)*8 + (k0&7);
      ushort4 uh; uh.x=f2bf(fh.x); uh.y=f2bf(fh.y); uh.z=f2bf(fh.z); uh.w=f2bf(fh.w);
      ushort4 us; us.x=f2bf(fs.x); us.y=f2bf(fs.y); us.z=f2bf(fs.z); us.w=f2bf(fs.w);
      *(ushort4*)&hl[idx] = uh;
      *(ushort4*)&sl[idx] = us;
    }
  }
  __syncthreads();

  const bf16x8* __restrict__ bph = (const bf16x8*)whp;
  const bf16x8* __restrict__ bps = (const bf16x8*)wsp;
  const int bbase = w*512 + lane;

  f32x4 acch[8], accs[8];
  #pragma unroll
  for(int ni=0;ni<8;ni++){ acch[ni]=(f32x4){0,0,0,0}; accs[ni]=(f32x4){0,0,0,0}; }

  #pragma unroll 2
  for(int kk=0;kk<16;kk++){
    bf16x8 ah = *(const bf16x8*)&hl[kk*512 + lane*8];
    bf16x8 as2 = *(const bf16x8*)&sl[kk*512 + lane*8];
    #pragma unroll
    for(int ni=0;ni<8;ni++){
      acch[ni] = __builtin_amdgcn_mfma_f32_16x16x32_bf16(ah,  bph[kk*2048 + bbase + ni*64], acch[ni], 0,0,0);
      accs[ni] = __builtin_amdgcn_mfma_f32_16x16x32_bf16(as2, bps[kk*2048 + bbase + ni*64], accs[ni], 0,0,0);
    }
  }

  float bhv[8], bsv[8], bvv[8], wbv[8];
  #pragma unroll
  for(int ni=0;ni<8;ni++){
    int col = w*128 + ni*16 + l15;
    bhv[ni] = bh[col]; bsv[ni] = bs[col]; bvv[ni] = bv[col]; wbv[ni] = wbeta[col];
  }
  float btsum[4];
  #pragma unroll
  for(int rr=0;rr<4;rr++){
    int row = l4*4 + rr;
    float bsum = 0.f;
    #pragma unroll
    for(int ni=0;ni<8;ni++){
      int col = w*128 + ni*16 + l15;
      float hp = acch[ni][rr] + bhv[ni];
      hpb[(size_t)(b0+row)*H_ + col] = hp + bvv[ni];
      float bt = fast_tanh((accs[ni][rr] + bsv[ni] + hp) * 0.70710678118654752f);
      bsum = fmaf(bt, wbv[ni], bsum);
    }
    btsum[rr] = bsum;
  }
  #pragma unroll
  for(int rr=0;rr<4;rr++){
    btsum[rr] += __shfl_xor(btsum[rr], 1);
    btsum[rr] += __shfl_xor(btsum[rr], 2);
    btsum[rr] += __shfl_xor(btsum[rr], 4);
    btsum[rr] += __shfl_xor(btsum[rr], 8);
    if(l15 == 0) zwp[w][l4*4+rr] = btsum[rr];
  }
  __syncthreads();
  if(tid < 16)
    beta[b0+tid] = zwp[0][tid] + zwp[1][tid] + zwp[2][tid] + zwp[3][tid] + bbeta_p[0];
}

// k_fused: one block/batch. N-split two-pass GEMM: pass 0 (cols 0-255) runs the
// staged K-pipeline (v -> swizzled bf16 LDS), pass 1 (cols 256-511) re-reads
// the staged A-tile. acc[4][4]=64 VGPR -> ~150 total -> 3 blocks/CU (12 waves).
__global__ __launch_bounds__(256, 3) void k_fused(
    const float* __restrict__ v, const ushort_* __restrict__ bpack,
    const float* __restrict__ hpb, const float* __restrict__ wz,
    const float* __restrict__ bz_p, const float* __restrict__ beta,
    const float* __restrict__ s, float* __restrict__ out)
{
  __shared__ __align__(16) ushort_ Av[49*512];   // 50KB bf16, swizzled granules
  __shared__ float zw[4][64];
  __shared__ float a_s[64];
  const int tid = threadIdx.x;
  const int w = tid >> 6, lane = tid & 63;
  const int l15 = lane & 15, l4 = lane >> 4;
  const int b = blockIdx.x;

  const f32x4* __restrict__ vsrc = (const f32x4*)(v + (size_t)b * T_ * H_);
  const bf16x8* __restrict__ bp = (const bf16x8*)bpack;
  // pass p, wave w, tile ni: frag = bp[kk*2048 + p*1024 + w*256 + ni*64 + lane]
  const int bbase = w*256 + lane;

  // staging map: thread covers rows {srow, srow+16, srow+32} (+row 48 if tid<16)
  const int srow = tid >> 4, c4 = tid & 15;
  const int slot = ((c4 >> 1) ^ (srow & 7));
  const int wsub = ((c4 & 1) << 3);

  // ---- prologue: stage chunk 0 (cols 0..63); nontemporal (v single-use)
  {
    f32x4 nf0 = __builtin_nontemporal_load(vsrc + (srow      )*128 + c4);
    f32x4 nf1 = __builtin_nontemporal_load(vsrc + (srow + 16 )*128 + c4);
    f32x4 nf2 = __builtin_nontemporal_load(vsrc + (srow + 32 )*128 + c4);
    f32x4 nf3;
    if(tid < 16) nf3 = __builtin_nontemporal_load(vsrc + 48*128 + c4);
    ushort4 u;
    u.x=f2bf(nf0[0]); u.y=f2bf(nf0[1]); u.z=f2bf(nf0[2]); u.w=f2bf(nf0[3]);
    *(ushort4*)((char*)Av + (srow   )*1024 + (slot<<4) + wsub) = u;
    u.x=f2bf(nf1[0]); u.y=f2bf(nf1[1]); u.z=f2bf(nf1[2]); u.w=f2bf(nf1[3]);
    *(ushort4*)((char*)Av + (srow+16)*1024 + (slot<<4) + wsub) = u;
    u.x=f2bf(nf2[0]); u.y=f2bf(nf2[1]); u.z=f2bf(nf2[2]); u.w=f2bf(nf2[3]);
    *(ushort4*)((char*)Av + (srow+32)*1024 + (slot<<4) + wsub) = u;
    if(tid < 16){
      u.x=f2bf(nf3[0]); u.y=f2bf(nf3[1]); u.z=f2bf(nf3[2]); u.w=f2bf(nf3[3]);
      *(ushort4*)((char*)Av + 48*1024 + (slot<<4) + wsub) = u;
    }
  }

  f32x4 acc[4][4];
  #pragma unroll
  for(int mi=0;mi<4;mi++)
    #pragma unroll
    for(int ni=0;ni<4;ni++) acc[mi][ni] = (f32x4){0.f,0.f,0.f,0.f};

  bf16x8 ba[4], bb[4];
  #pragma unroll
  for(int ni=0;ni<4;ni++) ba[ni] = bp[bbase + ni*64];      // kk=0, pass 0
  __syncthreads();

  // ---- pass 0: 8 chunks of 64 cols (two K=32 steps each), cols 0..255
  #pragma unroll 1
  for(int c=0;c<8;c++){
    // B for odd kstep (L2, consumed this chunk)
    #pragma unroll
    for(int ni=0;ni<4;ni++) bb[ni] = bp[(2*c+1)*2048 + bbase + ni*64];
    // next chunk's v loads (HBM; issued after all B consumed before them)
    f32x4 nf0, nf1, nf2, nf3;
    if(c < 7){
      nf0 = __builtin_nontemporal_load(vsrc + (srow      )*128 + (c+1)*16 + c4);
      nf1 = __builtin_nontemporal_load(vsrc + (srow + 16 )*128 + (c+1)*16 + c4);
      nf2 = __builtin_nontemporal_load(vsrc + (srow + 32 )*128 + (c+1)*16 + c4);
      if(tid < 16) nf3 = __builtin_nontemporal_load(vsrc + 48*128 + (c+1)*16 + c4);
    }
    bf16x8 af[4];
    // K-step 0 (kk=2c) with ba
    #pragma unroll
    for(int mi=0;mi<4;mi++){
      int row = (mi < 3) ? (mi*16 + l15) : 48;
      int g   = ((2*c)*4 + l4) ^ (row & 7);
      af[mi] = *(const bf16x8*)((const char*)Av + row*1024 + (g<<4));
    }
    __builtin_amdgcn_s_setprio(1);
    #pragma unroll
    for(int mi=0;mi<4;mi++)
      #pragma unroll
      for(int ni=0;ni<4;ni++)
        acc[mi][ni] = __builtin_amdgcn_mfma_f32_16x16x32_bf16(af[mi], ba[ni], acc[mi][ni], 0,0,0);
    __builtin_amdgcn_s_setprio(0);
    // refill ba for next chunk's even kstep (issued after nf; consumed after barrier)
    if(c < 7){
      #pragma unroll
      for(int ni=0;ni<4;ni++) ba[ni] = bp[(2*c+2)*2048 + bbase + ni*64];
    }
    // K-step 1 (kk=2c+1) with bb
    #pragma unroll
    for(int mi=0;mi<4;mi++){
      int row = (mi < 3) ? (mi*16 + l15) : 48;
      int g   = ((2*c+1)*4 + l4) ^ (row & 7);
      af[mi] = *(const bf16x8*)((const char*)Av + row*1024 + (g<<4));
    }
    __builtin_amdgcn_s_setprio(1);
    #pragma unroll
    for(int mi=0;mi<4;mi++)
      #pragma unroll
      for(int ni=0;ni<4;ni++)
        acc[mi][ni] = __builtin_amdgcn_mfma_f32_16x16x32_bf16(af[mi], bb[ni], acc[mi][ni], 0,0,0);
    __builtin_amdgcn_s_setprio(0);
    // write staged chunk (v loads had the MFMA phase to land)
    if(c < 7){
      const int cb = (c+1)*128;
      ushort4 u;
      u.x=f2bf(nf0[0]); u.y=f2bf(nf0[1]); u.z=f2bf(nf0[2]); u.w=f2bf(nf0[3]);
      *(ushort4*)((char*)Av + (srow   )*1024 + cb + (slot<<4) + wsub) = u;
      u.x=f2bf(nf1[0]); u.y=f2bf(nf1[1]); u.z=f2bf(nf1[2]); u.w=f2bf(nf1[3]);
      *(ushort4*)((char*)Av + (srow+16)*1024 + cb + (slot<<4) + wsub) = u;
      u.x=f2bf(nf2[0]); u.y=f2bf(nf2[1]); u.z=f2bf(nf2[2]); u.w=f2bf(nf2[3]);
      *(ushort4*)((char*)Av + (srow+32)*1024 + cb + (slot<<4) + wsub) = u;
      if(tid < 16){
        u.x=f2bf(nf3[0]); u.y=f2bf(nf3[1]); u.z=f2bf(nf3[2]); u.w=f2bf(nf3[3]);
        *(ushort4*)((char*)Av + 48*1024 + cb + (slot<<4) + wsub) = u;
      }
      __syncthreads();
    }
  }

  // ---- pass-0 z-partials (cols w*64 .. w*64+63)
  {
    float wzv[4], hp0[4];
    #pragma unroll
    for(int ni=0;ni<4;ni++){
      int col = w*64 + ni*16 + l15;
      wzv[ni] = wz[col];
      hp0[ni] = hpb[(size_t)b*H_ + col];
    }
    float zp[16];
    #pragma unroll
    for(int mi=0;mi<4;mi++)
      #pragma unroll
      for(int r=0;r<4;r++){
        float az = 0.f;
        #pragma unroll
        for(int ni=0;ni<4;ni++)
          az = fmaf(fast_tanh(acc[mi][ni][r] + hp0[ni]), wzv[ni], az);
        zp[mi*4+r] = az;
      }
    #pragma unroll
    for(int i=0;i<16;i++){
      zp[i] += __shfl_xor(zp[i], 1);
      zp[i] += __shfl_xor(zp[i], 2);
      zp[i] += __shfl_xor(zp[i], 4);
      zp[i] += __shfl_xor(zp[i], 8);
    }
    if(l15 == 0){
      #pragma unroll
      for(int mi=0;mi<4;mi++)
        #pragma unroll
        for(int r=0;r<4;r++)
          zw[w][mi*16 + l4*4 + r] = zp[mi*4+r];
    }
  }

  // ---- pass 1: cols 256..511, straight from staged LDS (no staging)
  #pragma unroll
  for(int mi=0;mi<4;mi++)
    #pragma unroll
    for(int ni=0;ni<4;ni++) acc[mi][ni] = (f32x4){0.f,0.f,0.f,0.f};

  #pragma unroll
  for(int ni=0;ni<4;ni++) ba[ni] = bp[1024 + bbase + ni*64];   // kk=0 pass 1

  #pragma unroll 1
  for(int k2=0;k2<8;k2++){
    #pragma unroll
    for(int ni=0;ni<4;ni++) bb[ni] = bp[(2*k2+1)*2048 + 1024 + bbase + ni*64];
    bf16x8 af[4];
    #pragma unroll
    for(int mi=0;mi<4;mi++){
      int row = (mi < 3) ? (mi*16 + l15) : 48;
      int g   = ((2*k2)*4 + l4) ^ (row & 7);
      af[mi] = *(const bf16x8*)((const char*)Av + row*1024 + (g<<4));
    }
    __builtin_amdgcn_s_setprio(1);
    #pragma unroll
    for(int mi=0;mi<4;mi++)
      #pragma unroll
      for(int ni=0;ni<4;ni++)
        acc[mi][ni] = __builtin_amdgcn_mfma_f32_16x16x32_bf16(af[mi], ba[ni], acc[mi][ni], 0,0,0);
    __builtin_amdgcn_s_setprio(0);
    if(k2 < 7){
      #pragma unroll
      for(int ni=0;ni<4;ni++) ba[ni] = bp[(2*k2+2)*2048 + 1024 + bbase + ni*64];
    }
    #pragma unroll
    for(int mi=0;mi<4;mi++){
      int row = (mi < 3) ? (mi*16 + l15) : 48;
      int g   = ((2*k2+1)*4 + l4) ^ (row & 7);
      af[mi] = *(const bf16x8*)((const char*)Av + row*1024 + (g<<4));
    }
    __builtin_amdgcn_s_setprio(1);
    #pragma unroll
    for(int mi=0;mi<4;mi++)
      #pragma unroll
      for(int ni=0;ni<4;ni++)
        acc[mi][ni] = __builtin_amdgcn_mfma_f32_16x16x32_bf16(af[mi], bb[ni], acc[mi][ni], 0,0,0);
    __builtin_amdgcn_s_setprio(0);
  }

  // ---- pass-1 z-partials (cols 256 + w*64 ..) accumulated into zw
  {
    float wzv[4], hp0[4];
    #pragma unroll
    for(int ni=0;ni<4;ni++){
      int col = 256 + w*64 + ni*16 + l15;
      wzv[ni] = wz[col];
      hp0[ni] = hpb[(size_t)b*H_ + col];
    }
    float zp[16];
    #pragma unroll
    for(int mi=0;mi<4;mi++)
      #pragma unroll
      for(int r=0;r<4;r++){
        float az = 0.f;
        #pragma unroll
        for(int ni=0;ni<4;ni++)
          az = fmaf(fast_tanh(acc[mi][ni][r] + hp0[ni]), wzv[ni], az);
        zp[mi*4+r] = az;
      }
    #pragma unroll
    for(int i=0;i<16;i++){
      zp[i] += __shfl_xor(zp[i], 1);
      zp[i] += __shfl_xor(zp[i], 2);
      zp[i] += __shfl_xor(zp[i], 4);
      zp[i] += __shfl_xor(zp[i], 8);
    }
    if(l15 == 0){
      #pragma unroll
      for(int mi=0;mi<4;mi++)
        #pragma unroll
        for(int r=0;r<4;r++)
          zw[w][mi*16 + l4*4 + r] += zp[mi*4+r];
    }
  }
  __syncthreads();

  // ---- softmax over [z(49), beta] (wave 0)
  if(tid < 64){
    float zv;
    if(tid < T_)       zv = zw[0][tid] + zw[1][tid] + zw[2][tid] + zw[3][tid] + bz_p[0];
    else if(tid == T_) zv = beta[b];
    else               zv = -3.0e38f;
    float m = zv;
    #pragma unroll
    for(int off=32;off>=1;off>>=1) m = fmaxf(m, __shfl_xor(m, off));
    float e = (tid <= T_) ? __expf(zv - m) : 0.f;
    float ssum = e;
    #pragma unroll
    for(int off=32;off>=1;off>>=1) ssum += __shfl_xor(ssum, off);
    a_s[tid] = e * __builtin_amdgcn_rcpf(ssum);
  }
  __syncthreads();

  // ---- PV: c[n] = sum_t a[t]*v_bf16[t][n] + a[49]*s[b][n]; 2 cols/thread
  const int n0 = tid * 2;
  float ax = 0.f, ay = 0.f;
  #pragma unroll 7
  for(int t=0;t<T_;t++){
    float at = a_s[t];
    unsigned int u = *(const unsigned int*)((const char*)Av + t*1024
                       + ((((n0>>3) ^ (t&7)))<<4) + ((n0&7)<<1));
    float x = __uint_as_float((u & 0xFFFFu) << 16);
    float y = __uint_as_float(u & 0xFFFF0000u);
    ax = fmaf(at, x, ax);
    ay = fmaf(at, y, ay);
  }
  float a49 = a_s[T_];
  float2 sv = ((const float2*)(s + (size_t)b*H_))[tid];
  ax = fmaf(a49, sv.x, ax);
  ay = fmaf(a49, sv.y, ay);
  float2 res; res.x = ax; res.y = ay;
  ((float2*)(out + (size_t)b*H_))[tid] = res;
}

extern "C" void kernel_launch(void* const* d_in, const int* in_sizes, int n_in,
                              void* d_out, int out_size, void* d_ws, size_t ws_size,
                              hipStream_t stream)
{
  const float* v   = (const float*)d_in[0];
  const float* h   = (const float*)d_in[1];
  const float* s   = (const float*)d_in[2];
  const float* Wh  = (const float*)d_in[3];
  const float* bh  = (const float*)d_in[4];
  const float* Wv  = (const float*)d_in[5];
  const float* bv  = (const float*)d_in[6];
  const float* wz  = (const float*)d_in[7];
  const float* bz  = (const float*)d_in[8];
  const float* Ws  = (const float*)d_in[9];
  const float* bs  = (const float*)d_in[10];
  const float* wb  = (const float*)d_in[11];
  const float* bbet= (const float*)d_in[12];
  float* out = (float*)d_out;

  float* hpb  = (float*)d_ws;                      // B*H f32
  float* beta = hpb + (size_t)B_*H_;               // B f32
  ushort_* bpack = (ushort_*)(beta + B_);          // Wv frag-packed bf16
  ushort_* whp   = bpack + (size_t)H_*H_;          // Wh frag-packed
  ushort_* wsp   = whp   + (size_t)H_*H_;          // Ws frag-packed

  k_pack <<<128, 256, 0, stream>>>(Wv, bpack);
  k_pack <<<128, 256, 0, stream>>>(Wh, whp);
  k_pack <<<128, 256, 0, stream>>>(Ws, wsp);
  k_proj2<<<B_/16, 256, 0, stream>>>(h, s, whp, wsp, bh, bs, bv, wb, bbet, hpb, beta);
  k_fused<<<B_, 256, 0, stream>>>(v, bpack, hpb, wz, bz, beta, s, out);
}